// Round 7
// baseline (496.096 us; speedup 1.0000x reference)
//
#include <hip/hip_runtime.h>

// NCC loss: five 9x9x9 box sums (I, J, I^2, J^2, I*J), stride 1, pad 4,
// count_include_pad (divisor 729), ncc = cov^2/(varI*varJ+eps), out = -mean.
// Shapes fixed: [2,1,192,192,192] fp32.
//
// R14: TWO SLICES PER BARRIER, ZERO extra register state.
// R8-R13 lesson: allocator pins 128 VGPR; any live-state growth spills
// (R13: waves_per_eu(2,2) ignored, 45MB spill). R7's residual gap to the
// ~56us LDS-pipe floor is non-overlap: per-slice 4-wave barrier rendezvous
// + serial YSTEP chain. This round amortizes the barrier over 2 slices:
//   XPHASE(2i) -> LOAD(2i+1) -> YSTEP(2i-2) -> XPHASE(2i+1) -> LOAD(2i+2)
//   -> YSTEP(2i-1) -> barrier
// The 24-float prefetch regs are consumed/refilled TWICE per body -> peak
// pressure == R7. Barriers 40 -> 21; two independent YSTEPs per body (ILP).
// Needs 4 LDS slice-buffers (slice mod 4): 56KB, 2 blocks/CU (= R7's
// achieved residency). Buffer index is uniform-dynamic (1 VALU/phase);
// row/col offsets stay immediate.
// XSW1 20 -> 21: xs1 WRITE pattern (20*xr+4*xq) hit only 8 banks (8-way);
// stride 21 spreads writes ~2-way, reads go 2->~3-way (net win; writes
// were the dominant conflict source, 1.18e7 cycles).
// Kept (verified absmax=0): rcp EMIT, else-zero LOAD, lgkm-only barrier,
// named-scalar rings, 9-body groups for static ring slot K, XCD swizzle,
// launch_bounds(256,2).

#define S    192
#define SS   (S * S)
#define TX   16
#define YT   32                  // y-tile; thread tyt owns y=2*tyt, 2*tyt+1
#define NTHR 256
#define KZ   32
#define RAD  4
#define WIN  9
#define NSL  (KZ + 2 * RAD)      // 40 slices
#define HXR  (YT + 2 * RAD)      // 40 halo rows
#define XSW  17                  // xs4 padded row stride (float4 units)
#define XSW1 21                  // xs1 padded row stride (floats)
#define NVOX (2.0 * S * S * S)

// LDS-only barrier: waves' DS ops complete (lgkmcnt) + rendezvous. No vmcnt
// drain -> global prefetch survives the barrier.
#define LDS_BARRIER() __asm__ __volatile__("s_waitcnt lgkmcnt(0)\n\ts_barrier" ::: "memory")

__global__ void ncc_init(double* ws) { ws[0] = 0.0; }

__global__ void ncc_final(const double* __restrict__ ws, float* __restrict__ out) {
    out[0] = (float)(-ws[0] / NVOX);
}

__device__ __forceinline__ float4 f4add(float4 a, float4 b) {
    return make_float4(a.x + b.x, a.y + b.y, a.z + b.z, a.w + b.w);
}
__device__ __forceinline__ float4 f4sub(float4 a, float4 b) {
    return make_float4(a.x - b.x, a.y - b.y, a.z - b.z, a.w - b.w);
}

__global__ __launch_bounds__(NTHR, 2) void ncc_main(const float* __restrict__ I,
                                                    const float* __restrict__ J,
                                                    double* __restrict__ ws) {
    // LDS ~56KB: xs4 4*40*17*16=43520 + xs1 4*40*21*4=13440 + red.
    __shared__ float4 xs4[4][HXR][XSW];    // (sI, sJ, sI2, sJ2), slice mod 4
    __shared__ float  xs1[4][HXR][XSW1];   // sIJ
    __shared__ float  red[4];

    const int tid = threadIdx.x;          // 0..255 (flat)
    const int tx  = tid & 15;
    const int tyt = tid >> 4;             // 0..15 -> outputs y=2*tyt, 2*tyt+1

    // XCD swizzle over 864 blocks: id&7 = XCD owns a 3x3 xy-patch, bijective.
    const int id  = blockIdx.x;           // 0..863
    const int xcd = id & 7;
    const int lo  = id >> 3;              // 0..107
    const int t   = lo % 9;
    const int bzq = lo / 9;               // 0..11
    const int bx  = (xcd & 3) * 3 + t % 3;     // 0..11
    const int by  = (xcd >> 2) * 3 + t / 3;    // 0..5
    const int b   = (bzq >= 6) ? 1 : 0;
    const int zc  = bzq - 6 * b;
    const int x0 = bx * TX, y0 = by * YT, z0 = zc * KZ;

    const float* Ib = I + (size_t)b * S * SS;
    const float* Jb = J + (size_t)b * S * SS;

    // x-tasks: 160 threads, task (row xr 0..39, quad xq 0..3) -> 4 x-outputs
    // from 12 input cols (4-aligned chunks, all-valid or all-invalid).
    const bool xtask = (tid < 4 * HXR);
    const int  xr  = tid >> 2;            // 0..39
    const int  xq  = tid & 3;
    const int  gy  = y0 - RAD + xr;
    const bool gyv = xtask && ((unsigned)gy < (unsigned)S);
    const int  c0  = x0 + 4 * xq - RAD;
    const bool cv0 = gyv && ((unsigned)(c0    ) < (unsigned)S);
    const bool cv1 = gyv && ((unsigned)(c0 + 4) < (unsigned)S);
    const bool cv2 = gyv && ((unsigned)(c0 + 8) < (unsigned)S);
    const ptrdiff_t rowoff = gyv ? ((ptrdiff_t)gy * S + c0) : 0;

    const float4 F40 = make_float4(0.f, 0.f, 0.f, 0.f);
    // Zero-initialized once: cv-invalid lanes stay 0 forever (cv invariant);
    // z-edge slices re-zero via the else branch (uniform, rare).
    float4 li0 = F40, li1 = F40, li2 = F40, lj0 = F40, lj1 = F40, lj2 = F40;

    auto LOAD = [&](int p) {
        const int zi = z0 - RAD + p;
        if (p < NSL && (unsigned)zi < (unsigned)S) {
            const float* rI = Ib + (size_t)zi * SS + rowoff;
            const float* rJ = Jb + (size_t)zi * SS + rowoff;
            if (cv0) { li0 = *(const float4*)(rI);     lj0 = *(const float4*)(rJ); }
            if (cv1) { li1 = *(const float4*)(rI + 4); lj1 = *(const float4*)(rJ + 4); }
            if (cv2) { li2 = *(const float4*)(rI + 8); lj2 = *(const float4*)(rJ + 8); }
        } else {
            li0 = li1 = li2 = lj0 = lj1 = lj2 = F40;
        }
    };

    // x-phase into buffer CB (uniform-dynamic 0..3).
    auto XPHASE = [&](int cb) {
        if (xtask) {
            const float iv[12] = { li0.x, li0.y, li0.z, li0.w,
                                   li1.x, li1.y, li1.z, li1.w,
                                   li2.x, li2.y, li2.z, li2.w };
            const float jv[12] = { lj0.x, lj0.y, lj0.z, lj0.w,
                                   lj1.x, lj1.y, lj1.z, lj1.w,
                                   lj2.x, lj2.y, lj2.z, lj2.w };
            float a = 0.f, bb = 0.f, c = 0.f, d = 0.f, e = 0.f;
            #pragma unroll
            for (int m = 0; m < WIN; ++m) {
                a += iv[m];
                bb += jv[m];
                c = fmaf(iv[m], iv[m], c);
                d = fmaf(jv[m], jv[m], d);
                e = fmaf(iv[m], jv[m], e);
            }
            #pragma unroll
            for (int k = 0; k < 4; ++k) {
                if (k > 0) {
                    a += iv[8 + k] - iv[k - 1];
                    bb += jv[8 + k] - jv[k - 1];
                    c += fmaf(iv[8 + k], iv[8 + k], -iv[k - 1] * iv[k - 1]);
                    d += fmaf(jv[8 + k], jv[8 + k], -jv[k - 1] * jv[k - 1]);
                    e += fmaf(iv[8 + k], jv[8 + k], -iv[k - 1] * jv[k - 1]);
                }
                xs4[cb][xr][4 * xq + k] = make_float4(a, bb, c, d);
                xs1[cb][xr][4 * xq + k] = e;
            }
        }
    };

    // z-rings as NAMED scalars (no arrays -> no scratch demotion possible).
    float4 a4_0 = F40, a4_1 = F40, a4_2 = F40, a4_3 = F40, a4_4 = F40,
           a4_5 = F40, a4_6 = F40, a4_7 = F40, a4_8 = F40;
    float  a1_0 = 0.f, a1_1 = 0.f, a1_2 = 0.f, a1_3 = 0.f, a1_4 = 0.f,
           a1_5 = 0.f, a1_6 = 0.f, a1_7 = 0.f, a1_8 = 0.f;
    float4 b4_0 = F40, b4_1 = F40, b4_2 = F40, b4_3 = F40, b4_4 = F40,
           b4_5 = F40, b4_6 = F40, b4_7 = F40, b4_8 = F40;
    float  b1_0 = 0.f, b1_1 = 0.f, b1_2 = 0.f, b1_3 = 0.f, b1_4 = 0.f,
           b1_5 = 0.f, b1_6 = 0.f, b1_7 = 0.f, b1_8 = 0.f;
    float4 runA4 = F40, runB4 = F40;
    float  runA1 = 0.f, runB1 = 0.f;
    float  acc = 0.f;
    const int yA = 2 * tyt;               // taps yA..yA+9 cover both outputs

    // One-instruction reciprocal (v_rcp_f32, ~1 ulp): final |err| ~1e-10 abs.
#define EMIT(R4, R1) do {                                                   \
        const float inv_ = 1.0f / 729.0f;                                   \
        const float mI_ = (R4).x * inv_, mJ_ = (R4).y * inv_;               \
        const float vI_ = (R4).z * inv_ - mI_ * mI_;                        \
        const float vJ_ = (R4).w * inv_ - mJ_ * mJ_;                        \
        const float cIJ_ = (R1) * inv_ - mI_ * mJ_;                         \
        acc = fmaf(cIJ_ * cIJ_,                                             \
                   __builtin_amdgcn_rcpf(vI_ * vJ_ + 1e-5f), acc);          \
    } while (0)

    // y-phase from buffer PB (uniform-dynamic), STATIC ring slot K.
#define YSTEP(PB, K, DOEMIT) do {                                           \
        const int pb_ = (PB);                                               \
        const float4 t0_4 = xs4[pb_][yA][tx];                               \
        const float  t0_1 = xs1[pb_][yA][tx];                               \
        float4 s4 = t0_4;                                                   \
        float  s1 = t0_1;                                                   \
        _Pragma("unroll")                                                   \
        for (int j_ = 1; j_ < WIN; ++j_) {                                  \
            s4 = f4add(s4, xs4[pb_][yA + j_][tx]);                          \
            s1 += xs1[pb_][yA + j_][tx];                                    \
        }                                                                   \
        const float4 t9_4 = xs4[pb_][yA + WIN][tx];                         \
        const float  t9_1 = xs1[pb_][yA + WIN][tx];                         \
        const float4 sB4 = f4add(f4sub(s4, t0_4), t9_4);                    \
        const float  sB1 = s1 - t0_1 + t9_1;                                \
        runA4 = f4add(runA4, f4sub(s4, a4_##K));   a4_##K = s4;             \
        runA1 += s1 - a1_##K;                      a1_##K = s1;             \
        runB4 = f4add(runB4, f4sub(sB4, b4_##K));  b4_##K = sB4;            \
        runB1 += sB1 - b1_##K;                     b1_##K = sB1;            \
        if (DOEMIT) { EMIT(runA4, runA1); EMIT(runB4, runB1); }             \
    } while (0)

    // Body i (POS = i-1-9g): slices x(2i), x(2i+1); y(2i-2), y(2i-1).
    // Write bufs wb, wb+1 = (2i)&3, (2i+1)&3; read bufs rb=wb^2, rb+1.
    // Prefetch regs consumed+refilled twice -> peak pressure == R7.
#define BODY(POS, K1, K2, EM1, EM2) do {                                    \
        const int ip_ = ((POS) + 1 + gpar) & 1;                             \
        const int wb_ = ip_ << 1;                                           \
        const int rb_ = wb_ ^ 2;                                            \
        XPHASE(wb_);             /* x(2i): regs from prev body/prologue */  \
        LOAD(idx + 1);           /* slice 2i+1 into freed regs */           \
        YSTEP(rb_, K1, EM1);     /* y(2i-2), covers vmcnt of LOAD */        \
        XPHASE(wb_ + 1);         /* x(2i+1) */                              \
        LOAD(idx + 2);           /* slice 2i+2; crosses the barrier */      \
        YSTEP(rb_ + 1, K2, EM2); /* y(2i-1) */                              \
        LDS_BARRIER();                                                      \
        idx += 2;                                                           \
    } while (0)

    // Prologue: slices 0,1 staged into bufs 0,1; slice 2 in regs.
    LOAD(0);
    XPHASE(0);
    LOAD(1);
    XPHASE(1);
    LOAD(2);
    LDS_BARRIER();

    // Bodies i=1..18 as 2 groups of 9 (K static per position; buffer pair
    // alternates with (pos+1+gpar)&1 since 9 is odd). Emit from p>=8.
    int idx = 2;
    #pragma unroll 1
    for (int g = 0; g < 2; ++g) {
        const int  gpar = g & 1;
        const bool em = (g != 0);
        BODY(0, 0, 1, em, em);       // y p=2i-2,2i-1
        BODY(1, 2, 3, em, em);
        BODY(2, 4, 5, em, em);
        BODY(3, 6, 7, em, em);
        BODY(4, 8, 0, true, true);   // p=8,9: first emits
        BODY(5, 1, 2, true, true);
        BODY(6, 3, 4, true, true);
        BODY(7, 5, 6, true, true);
        BODY(8, 7, 8, true, true);
    }
    // Tail body i=19: x(38),x(39); y(36),y(37) K=0,1. wb=(38)&3=2.
    {
        const int gpar = 1;          // (18+1+1)&1 = 0 -> wb=0? compute direct:
        (void)gpar;
        XPHASE(2);                   // slice 38 -> buf 2
        LOAD(idx + 1);               // slice 39
        YSTEP(0, 0, true);           // y(36), buf 36&3=0
        XPHASE(3);                   // slice 39 -> buf 3
        LOAD(idx + 2);               // p=40 -> guarded else-zero (harmless)
        YSTEP(1, 1, true);           // y(37), buf 1
        LDS_BARRIER();
    }
    // Epilogue: y(38) buf 2 K=2; y(39) buf 3 K=3.
    YSTEP(2, 2, true);
    YSTEP(3, 3, true);
#undef BODY
#undef YSTEP
#undef EMIT

    // Block reduction: wave shuffle -> LDS -> one double atomic.
    float v = acc;
    #pragma unroll
    for (int off = 32; off >= 1; off >>= 1)
        v += __shfl_down(v, off, 64);
    const int lane = tid & 63;
    const int wid  = tid >> 6;
    if (lane == 0) red[wid] = v;
    __syncthreads();
    if (tid == 0) {
        atomicAdd(ws, (double)(red[0] + red[1] + red[2] + red[3]));
    }
}

extern "C" void kernel_launch(void* const* d_in, const int* in_sizes, int n_in,
                              void* d_out, int out_size, void* d_ws, size_t ws_size,
                              hipStream_t stream) {
    const float* I = (const float*)d_in[0];   // y_pred
    const float* J = (const float*)d_in[1];   // y_true
    double* ws = (double*)d_ws;
    float* out = (float*)d_out;

    hipLaunchKernelGGL(ncc_init, dim3(1), dim3(1), 0, stream, ws);

    hipLaunchKernelGGL(ncc_main, dim3(12 * 6 * 12), dim3(NTHR), 0, stream,
                       I, J, ws);

    hipLaunchKernelGGL(ncc_final, dim3(1), dim3(1), 0, stream, ws, out);
}

// Round 8
// 234.780 us; speedup vs baseline: 2.1130x; 2.1130x over previous
//
#include <hip/hip_runtime.h>

// NCC loss: five 9x9x9 box sums (I, J, I^2, J^2, I*J), stride 1, pad 4,
// count_include_pad (divisor 729), ncc = cov^2/(varI*varJ+eps), out = -mean.
// Shapes fixed: [2,1,192,192,192] fp32.
//
// R15 = R7 VERBATIM STRUCTURE + two strictly-local, pressure-REDUCING
// micro-opts (each verified absmax=0 in R8-R14, never tested unbundled):
//  (1) EMIT: IEEE divide -> fmaf(cIJ^2, v_rcp_f32, acc). Removes ~10 VALU
//      x2 emits/slice AND the div sequence's live temps. |err| ~1e-10 abs.
//  (2) LOAD zeroing -> else-branch (uniform, edge-only). Saves 24
//      v_mov/slice steady-state; cv-invalid lanes stay 0 by induction.
// R8-R14 law (6 rounds of evidence): allocator pins 128 VGPR; ANY widening
// of the scheduling window (static 18/36-unroll, 3rd ring, 2-slice bodies,
// wave-privatization) spills rings -> 0.5-1.3GB scratch traffic. R7 sits
// exactly at the pressure ceiling; only local simplifications are safe.
// Carried from R7: dynamic buffer parity, 4x9+tail loop, lgkmcnt-only
// slice barrier (global prefetch survives), xs1 stride 20, named-scalar
// z-rings, 16x32 tile, 2 y-outputs/thread, direct-global float4 x-phase,
// XCD swizzle (FETCH == compulsory 116MB).

#define S    192
#define SS   (S * S)
#define TX   16
#define YT   32                  // y-tile; thread (tx,tyt) owns y=2*tyt,2*tyt+1
#define NTHR 256
#define KZ   32
#define RAD  4
#define WIN  9
#define NSL  (KZ + 2 * RAD)      // 40
#define HXR  (YT + 2 * RAD)      // 40 halo rows
#define XSW  17                  // xs4 padded row stride (float4 units)
#define XSW1 20                  // xs1 padded row stride (floats): banks 8t+tx
#define NVOX (2.0 * S * S * S)

// LDS-only barrier: waves' DS ops complete (lgkmcnt) + rendezvous. No vmcnt
// drain -> global prefetch survives the barrier.
#define LDS_BARRIER() __asm__ __volatile__("s_waitcnt lgkmcnt(0)\n\ts_barrier" ::: "memory")

__global__ void ncc_init(double* ws) { ws[0] = 0.0; }

__global__ void ncc_final(const double* __restrict__ ws, float* __restrict__ out) {
    out[0] = (float)(-ws[0] / NVOX);
}

__device__ __forceinline__ float4 f4add(float4 a, float4 b) {
    return make_float4(a.x + b.x, a.y + b.y, a.z + b.z, a.w + b.w);
}
__device__ __forceinline__ float4 f4sub(float4 a, float4 b) {
    return make_float4(a.x - b.x, a.y - b.y, a.z - b.z, a.w - b.w);
}

__global__ __launch_bounds__(NTHR, 2) void ncc_main(const float* __restrict__ I,
                                                    const float* __restrict__ J,
                                                    double* __restrict__ ws) {
    // LDS ~28 KB: xs4 2*40*17*16 + xs1 2*40*20*4 + red
    __shared__ float4 xs4[2][HXR][XSW];    // (sI, sJ, sI2, sJ2)
    __shared__ float  xs1[2][HXR][XSW1];   // sIJ
    __shared__ float  red[4];

    const int tid = threadIdx.x;          // 0..255 (flat)
    const int tx  = tid & 15;
    const int tyt = tid >> 4;             // 0..15 -> outputs y=2*tyt, 2*tyt+1

    // XCD swizzle over 864 blocks: id&7 = XCD owns a 3x3 xy-patch, bijective.
    const int id  = blockIdx.x;           // 0..863
    const int xcd = id & 7;
    const int lo  = id >> 3;              // 0..107
    const int t   = lo % 9;
    const int bzq = lo / 9;               // 0..11
    const int bx  = (xcd & 3) * 3 + t % 3;     // 0..11
    const int by  = (xcd >> 2) * 3 + t / 3;    // 0..5
    const int b   = (bzq >= 6) ? 1 : 0;
    const int zc  = bzq - 6 * b;
    const int x0 = bx * TX, y0 = by * YT, z0 = zc * KZ;

    const float* Ib = I + (size_t)b * S * SS;
    const float* Jb = J + (size_t)b * S * SS;

    // x-tasks: 160 threads, task (row xr 0..39, quad xq 0..3) -> 4 x-outputs
    // from 12 input cols (4-aligned chunks, all-valid or all-invalid).
    const bool xtask = (tid < 4 * HXR);
    const int  xr  = tid >> 2;            // 0..39
    const int  xq  = tid & 3;
    const int  gy  = y0 - RAD + xr;
    const bool gyv = xtask && ((unsigned)gy < (unsigned)S);
    const int  c0  = x0 + 4 * xq - RAD;
    const bool cv0 = gyv && ((unsigned)(c0    ) < (unsigned)S);
    const bool cv1 = gyv && ((unsigned)(c0 + 4) < (unsigned)S);
    const bool cv2 = gyv && ((unsigned)(c0 + 8) < (unsigned)S);
    const ptrdiff_t rowoff = gyv ? ((ptrdiff_t)gy * S + c0) : 0;

    const float4 F40 = make_float4(0.f, 0.f, 0.f, 0.f);
    // Zero-initialized once: cv-invalid lanes stay 0 forever (cv invariant);
    // z-edge / past-end slices re-zero via the else branch (uniform, rare).
    float4 li0 = F40, li1 = F40, li2 = F40, lj0 = F40, lj1 = F40, lj2 = F40;

    auto LOAD = [&](int p) {
        const int zi = z0 - RAD + p;
        if (p < NSL && (unsigned)zi < (unsigned)S) {
            const float* rI = Ib + (size_t)zi * SS + rowoff;
            const float* rJ = Jb + (size_t)zi * SS + rowoff;
            if (cv0) { li0 = *(const float4*)(rI);     lj0 = *(const float4*)(rJ); }
            if (cv1) { li1 = *(const float4*)(rI + 4); lj1 = *(const float4*)(rJ + 4); }
            if (cv2) { li2 = *(const float4*)(rI + 8); lj2 = *(const float4*)(rJ + 8); }
        } else {
            li0 = li1 = li2 = lj0 = lj1 = lj2 = F40;
        }
    };

    auto XPHASE = [&](int p) {
        if (xtask) {
            const float iv[12] = { li0.x, li0.y, li0.z, li0.w,
                                   li1.x, li1.y, li1.z, li1.w,
                                   li2.x, li2.y, li2.z, li2.w };
            const float jv[12] = { lj0.x, lj0.y, lj0.z, lj0.w,
                                   lj1.x, lj1.y, lj1.z, lj1.w,
                                   lj2.x, lj2.y, lj2.z, lj2.w };
            float a = 0.f, bb = 0.f, c = 0.f, d = 0.f, e = 0.f;
            #pragma unroll
            for (int m = 0; m < WIN; ++m) {
                a += iv[m];
                bb += jv[m];
                c = fmaf(iv[m], iv[m], c);
                d = fmaf(jv[m], jv[m], d);
                e = fmaf(iv[m], jv[m], e);
            }
            const int cb = p & 1;
            #pragma unroll
            for (int k = 0; k < 4; ++k) {
                if (k > 0) {
                    a += iv[8 + k] - iv[k - 1];
                    bb += jv[8 + k] - jv[k - 1];
                    c += fmaf(iv[8 + k], iv[8 + k], -iv[k - 1] * iv[k - 1]);
                    d += fmaf(jv[8 + k], jv[8 + k], -jv[k - 1] * jv[k - 1]);
                    e += fmaf(iv[8 + k], jv[8 + k], -iv[k - 1] * jv[k - 1]);
                }
                xs4[cb][xr][4 * xq + k] = make_float4(a, bb, c, d);
                xs1[cb][xr][4 * xq + k] = e;
            }
        }
    };

    // z-rings as NAMED scalars (no arrays -> no scratch demotion possible).
    float4 a4_0 = F40, a4_1 = F40, a4_2 = F40, a4_3 = F40, a4_4 = F40,
           a4_5 = F40, a4_6 = F40, a4_7 = F40, a4_8 = F40;
    float  a1_0 = 0.f, a1_1 = 0.f, a1_2 = 0.f, a1_3 = 0.f, a1_4 = 0.f,
           a1_5 = 0.f, a1_6 = 0.f, a1_7 = 0.f, a1_8 = 0.f;
    float4 b4_0 = F40, b4_1 = F40, b4_2 = F40, b4_3 = F40, b4_4 = F40,
           b4_5 = F40, b4_6 = F40, b4_7 = F40, b4_8 = F40;
    float  b1_0 = 0.f, b1_1 = 0.f, b1_2 = 0.f, b1_3 = 0.f, b1_4 = 0.f,
           b1_5 = 0.f, b1_6 = 0.f, b1_7 = 0.f, b1_8 = 0.f;
    float4 runA4 = F40, runB4 = F40;
    float  runA1 = 0.f, runB1 = 0.f;
    float  acc = 0.f;
    const int yA = 2 * tyt;               // taps yA..yA+9 cover both outputs

    // One-instruction reciprocal (v_rcp_f32, ~1 ulp): final |err| ~1e-10 abs.
#define EMIT(R4, R1) do {                                                   \
        const float inv_ = 1.0f / 729.0f;                                   \
        const float mI_ = (R4).x * inv_, mJ_ = (R4).y * inv_;               \
        const float vI_ = (R4).z * inv_ - mI_ * mI_;                        \
        const float vJ_ = (R4).w * inv_ - mJ_ * mJ_;                        \
        const float cIJ_ = (R1) * inv_ - mI_ * mJ_;                         \
        acc = fmaf(cIJ_ * cIJ_,                                             \
                   __builtin_amdgcn_rcpf(vI_ * vJ_ + 1e-5f), acc);          \
    } while (0)

#define YSTEP(P, K) do {                                                    \
        const int pb_ = (P) & 1;                                            \
        float4 t0_4 = xs4[pb_][yA][tx];                                     \
        float  t0_1 = xs1[pb_][yA][tx];                                     \
        float4 s4 = t0_4;                                                   \
        float  s1 = t0_1;                                                   \
        _Pragma("unroll")                                                   \
        for (int j_ = 1; j_ < WIN; ++j_) {                                  \
            s4 = f4add(s4, xs4[pb_][yA + j_][tx]);                          \
            s1 += xs1[pb_][yA + j_][tx];                                    \
        }                                                                   \
        const float4 t9_4 = xs4[pb_][yA + WIN][tx];                         \
        const float  t9_1 = xs1[pb_][yA + WIN][tx];                         \
        const float4 sB4 = f4add(f4sub(s4, t0_4), t9_4);                    \
        const float  sB1 = s1 - t0_1 + t9_1;                                \
        runA4 = f4add(runA4, f4sub(s4, a4_##K));   a4_##K = s4;             \
        runA1 += s1 - a1_##K;                      a1_##K = s1;             \
        runB4 = f4add(runB4, f4sub(sB4, b4_##K));  b4_##K = sB4;            \
        runB1 += sB1 - b1_##K;                     b1_##K = sB1;            \
        if ((P) >= 2 * RAD) { EMIT(runA4, runA1); EMIT(runB4, runB1); }     \
    } while (0)

#define BODY(K) { YSTEP(idx - 1, K); XPHASE(idx); LOAD(idx + 1);            \
                  LDS_BARRIER(); ++idx; }

    // Pipeline: [y(idx-1) | x(idx) | load(idx+1) | lds-barrier] per slice.
    LOAD(0);
    XPHASE(0);
    LOAD(1);
    LDS_BARRIER();

    int idx = 1;
    #pragma unroll 1
    for (int g = 0; g < 4; ++g) {        // y-index p=idx-1 = 0..35, K=p%9
        BODY(0) BODY(1) BODY(2) BODY(3) BODY(4)
        BODY(5) BODY(6) BODY(7) BODY(8)
    }
    BODY(0) BODY(1) BODY(2)              // p = 36,37,38 -> K 0,1,2
    YSTEP(NSL - 1, 3);                   // p = 39 -> 39%9 = 3
#undef BODY
#undef YSTEP
#undef EMIT

    // Block reduction: wave shuffle -> LDS -> one double atomic.
    // (Full __syncthreads here is fine: once per block, nothing to prefetch.)
    float v = acc;
    #pragma unroll
    for (int off = 32; off >= 1; off >>= 1)
        v += __shfl_down(v, off, 64);
    const int lane = tid & 63;
    const int wid  = tid >> 6;
    if (lane == 0) red[wid] = v;
    __syncthreads();
    if (tid == 0) {
        atomicAdd(ws, (double)(red[0] + red[1] + red[2] + red[3]));
    }
}

extern "C" void kernel_launch(void* const* d_in, const int* in_sizes, int n_in,
                              void* d_out, int out_size, void* d_ws, size_t ws_size,
                              hipStream_t stream) {
    const float* I = (const float*)d_in[0];   // y_pred
    const float* J = (const float*)d_in[1];   // y_true
    double* ws = (double*)d_ws;
    float* out = (float*)d_out;

    hipLaunchKernelGGL(ncc_init, dim3(1), dim3(1), 0, stream, ws);

    hipLaunchKernelGGL(ncc_main, dim3(12 * 6 * 12), dim3(NTHR), 0, stream,
                       I, J, ws);

    hipLaunchKernelGGL(ncc_final, dim3(1), dim3(1), 0, stream, ws, out);
}

// Round 9
// 200.925 us; speedup vs baseline: 2.4691x; 1.1685x over previous
//
#include <hip/hip_runtime.h>

// NCC loss: five 9x9x9 box sums (I, J, I^2, J^2, I*J), stride 1, pad 4,
// count_include_pad (divisor 729), ncc = cov^2/(varI*varJ+eps), out = -mean.
// Shapes fixed: [2,1,192,192,192] fp32.
//
// R16 = R7 byte-identical EXCEPT the EMIT divide -> v_rcp_f32.
// R15 POST-MORTEM (the key finding of R8-R15): the "else-branch LOAD
// zeroing" was the hidden poison in every clean-but-slow variant (R12: 144,
// R15: 144 vs R7: 108us; VALUBusy 44->30%). R7's unconditional li*=0 is a
// FULL redefinition per slice -> fresh SSA defs -> the scheduler hoists
// slice-(p+1) global loads above YSTEP/XPHASE(p) into separate physical
// regs (compiler-level double-buffered prefetch, the reason R7 sits at 128
// VGPR). Else-zeroing made li* loop-carried (phi: cv-false lanes preserve
// old value), pinning loads to late-issue with only ~300cy of cover for
// ~500cy latency -> ~+36us exposed stall. LESSON: the 24 v_movs/slice ARE
// the prefetch renaming mechanism. Keep them.
// The rcp-EMIT change is pressure-REDUCING (drops div_scale/fmas/fixup
// temps + ~20 VALU/slice) and numerically verified (absmax=0 in R8-R15,
// |err| ~1e-10): tested here in isolation.
// Carried from R7 verbatim: unconditional-zero LOAD, dynamic buffer parity,
// 4x9+tail loop, lgkmcnt-only slice barrier (global prefetch survives),
// xs1 stride 20 (2-way = free), named-scalar z-rings, 16x32 tile, 2
// y-outputs/thread, direct-global float4 x-phase, XCD swizzle (FETCH ==
// compulsory 116MB), launch_bounds(256,2).

#define S    192
#define SS   (S * S)
#define TX   16
#define YT   32                  // y-tile; thread (tx,tyt) owns y=2*tyt,2*tyt+1
#define NTHR 256
#define KZ   32
#define RAD  4
#define WIN  9
#define NSL  (KZ + 2 * RAD)      // 40
#define HXR  (YT + 2 * RAD)      // 40 halo rows
#define XSW  17                  // xs4 padded row stride (float4 units)
#define XSW1 20                  // xs1 padded row stride (floats): banks 8t+tx
#define NVOX (2.0 * S * S * S)

// LDS-only barrier: waves' DS ops complete (lgkmcnt) + rendezvous. No vmcnt
// drain -> global prefetch survives the barrier.
#define LDS_BARRIER() __asm__ __volatile__("s_waitcnt lgkmcnt(0)\n\ts_barrier" ::: "memory")

__global__ void ncc_init(double* ws) { ws[0] = 0.0; }

__global__ void ncc_final(const double* __restrict__ ws, float* __restrict__ out) {
    out[0] = (float)(-ws[0] / NVOX);
}

__device__ __forceinline__ float4 f4add(float4 a, float4 b) {
    return make_float4(a.x + b.x, a.y + b.y, a.z + b.z, a.w + b.w);
}
__device__ __forceinline__ float4 f4sub(float4 a, float4 b) {
    return make_float4(a.x - b.x, a.y - b.y, a.z - b.z, a.w - b.w);
}

__global__ __launch_bounds__(NTHR, 2) void ncc_main(const float* __restrict__ I,
                                                    const float* __restrict__ J,
                                                    double* __restrict__ ws) {
    // LDS ~28 KB: xs4 2*40*17*16 + xs1 2*40*20*4 + red
    __shared__ float4 xs4[2][HXR][XSW];    // (sI, sJ, sI2, sJ2)
    __shared__ float  xs1[2][HXR][XSW1];   // sIJ
    __shared__ float  red[4];

    const int tid = threadIdx.x;          // 0..255 (flat)
    const int tx  = tid & 15;
    const int tyt = tid >> 4;             // 0..15 -> outputs y=2*tyt, 2*tyt+1

    // XCD swizzle over 864 blocks: id&7 = XCD owns a 3x3 xy-patch, bijective.
    const int id  = blockIdx.x;           // 0..863
    const int xcd = id & 7;
    const int lo  = id >> 3;              // 0..107
    const int t   = lo % 9;
    const int bzq = lo / 9;               // 0..11
    const int bx  = (xcd & 3) * 3 + t % 3;     // 0..11
    const int by  = (xcd >> 2) * 3 + t / 3;    // 0..5
    const int b   = (bzq >= 6) ? 1 : 0;
    const int zc  = bzq - 6 * b;
    const int x0 = bx * TX, y0 = by * YT, z0 = zc * KZ;

    const float* Ib = I + (size_t)b * S * SS;
    const float* Jb = J + (size_t)b * S * SS;

    // x-tasks: 160 threads, task (row xr 0..39, quad xq 0..3) -> 4 x-outputs
    // from 12 input cols (4-aligned chunks, all-valid or all-invalid).
    const bool xtask = (tid < 4 * HXR);
    const int  xr  = tid >> 2;            // 0..39
    const int  xq  = tid & 3;
    const int  gy  = y0 - RAD + xr;
    const bool gyv = xtask && ((unsigned)gy < (unsigned)S);
    const int  c0  = x0 + 4 * xq - RAD;
    const bool cv0 = gyv && ((unsigned)(c0    ) < (unsigned)S);
    const bool cv1 = gyv && ((unsigned)(c0 + 4) < (unsigned)S);
    const bool cv2 = gyv && ((unsigned)(c0 + 8) < (unsigned)S);
    const ptrdiff_t rowoff = gyv ? ((ptrdiff_t)gy * S + c0) : 0;

    float4 li0, li1, li2, lj0, lj1, lj2;

    auto LOAD = [&](int p) {
        // Unconditional zeroing: full redefinition -> fresh SSA values each
        // slice -> compiler hoists these loads early into renamed physical
        // regs (prefetch). DO NOT convert to else-branch zeroing (R15: +36us).
        li0 = li1 = li2 = lj0 = lj1 = lj2 = make_float4(0.f, 0.f, 0.f, 0.f);
        if (p < NSL) {
            const int zi = z0 - RAD + p;
            if ((unsigned)zi < (unsigned)S) {
                const float* rI = Ib + (size_t)zi * SS + rowoff;
                const float* rJ = Jb + (size_t)zi * SS + rowoff;
                if (cv0) { li0 = *(const float4*)(rI);     lj0 = *(const float4*)(rJ); }
                if (cv1) { li1 = *(const float4*)(rI + 4); lj1 = *(const float4*)(rJ + 4); }
                if (cv2) { li2 = *(const float4*)(rI + 8); lj2 = *(const float4*)(rJ + 8); }
            }
        }
    };

    auto XPHASE = [&](int p) {
        if (xtask) {
            const float iv[12] = { li0.x, li0.y, li0.z, li0.w,
                                   li1.x, li1.y, li1.z, li1.w,
                                   li2.x, li2.y, li2.z, li2.w };
            const float jv[12] = { lj0.x, lj0.y, lj0.z, lj0.w,
                                   lj1.x, lj1.y, lj1.z, lj1.w,
                                   lj2.x, lj2.y, lj2.z, lj2.w };
            float a = 0.f, bb = 0.f, c = 0.f, d = 0.f, e = 0.f;
            #pragma unroll
            for (int m = 0; m < WIN; ++m) {
                a += iv[m];
                bb += jv[m];
                c = fmaf(iv[m], iv[m], c);
                d = fmaf(jv[m], jv[m], d);
                e = fmaf(iv[m], jv[m], e);
            }
            const int cb = p & 1;
            #pragma unroll
            for (int k = 0; k < 4; ++k) {
                if (k > 0) {
                    a += iv[8 + k] - iv[k - 1];
                    bb += jv[8 + k] - jv[k - 1];
                    c += fmaf(iv[8 + k], iv[8 + k], -iv[k - 1] * iv[k - 1]);
                    d += fmaf(jv[8 + k], jv[8 + k], -jv[k - 1] * jv[k - 1]);
                    e += fmaf(iv[8 + k], jv[8 + k], -iv[k - 1] * jv[k - 1]);
                }
                xs4[cb][xr][4 * xq + k] = make_float4(a, bb, c, d);
                xs1[cb][xr][4 * xq + k] = e;
            }
        }
    };

    // z-rings as NAMED scalars (no arrays -> no scratch demotion possible).
    const float4 F40 = make_float4(0.f, 0.f, 0.f, 0.f);
    float4 a4_0 = F40, a4_1 = F40, a4_2 = F40, a4_3 = F40, a4_4 = F40,
           a4_5 = F40, a4_6 = F40, a4_7 = F40, a4_8 = F40;
    float  a1_0 = 0.f, a1_1 = 0.f, a1_2 = 0.f, a1_3 = 0.f, a1_4 = 0.f,
           a1_5 = 0.f, a1_6 = 0.f, a1_7 = 0.f, a1_8 = 0.f;
    float4 b4_0 = F40, b4_1 = F40, b4_2 = F40, b4_3 = F40, b4_4 = F40,
           b4_5 = F40, b4_6 = F40, b4_7 = F40, b4_8 = F40;
    float  b1_0 = 0.f, b1_1 = 0.f, b1_2 = 0.f, b1_3 = 0.f, b1_4 = 0.f,
           b1_5 = 0.f, b1_6 = 0.f, b1_7 = 0.f, b1_8 = 0.f;
    float4 runA4 = F40, runB4 = F40;
    float  runA1 = 0.f, runB1 = 0.f;
    float  acc = 0.f;
    const int yA = 2 * tyt;               // taps yA..yA+9 cover both outputs

    // One-instruction reciprocal (v_rcp_f32, ~1 ulp): final |err| ~1e-10 abs.
    // Verified absmax=0 across R8-R15; also drops the div sequence's temps.
#define EMIT(R4, R1) do {                                                   \
        const float inv_ = 1.0f / 729.0f;                                   \
        const float mI_ = (R4).x * inv_, mJ_ = (R4).y * inv_;               \
        const float vI_ = (R4).z * inv_ - mI_ * mI_;                        \
        const float vJ_ = (R4).w * inv_ - mJ_ * mJ_;                        \
        const float cIJ_ = (R1) * inv_ - mI_ * mJ_;                         \
        acc = fmaf(cIJ_ * cIJ_,                                             \
                   __builtin_amdgcn_rcpf(vI_ * vJ_ + 1e-5f), acc);          \
    } while (0)

#define YSTEP(P, K) do {                                                    \
        const int pb_ = (P) & 1;                                            \
        float4 t0_4 = xs4[pb_][yA][tx];                                     \
        float  t0_1 = xs1[pb_][yA][tx];                                     \
        float4 s4 = t0_4;                                                   \
        float  s1 = t0_1;                                                   \
        _Pragma("unroll")                                                   \
        for (int j_ = 1; j_ < WIN; ++j_) {                                  \
            s4 = f4add(s4, xs4[pb_][yA + j_][tx]);                          \
            s1 += xs1[pb_][yA + j_][tx];                                    \
        }                                                                   \
        const float4 t9_4 = xs4[pb_][yA + WIN][tx];                         \
        const float  t9_1 = xs1[pb_][yA + WIN][tx];                         \
        const float4 sB4 = f4add(f4sub(s4, t0_4), t9_4);                    \
        const float  sB1 = s1 - t0_1 + t9_1;                                \
        runA4 = f4add(runA4, f4sub(s4, a4_##K));   a4_##K = s4;             \
        runA1 += s1 - a1_##K;                      a1_##K = s1;             \
        runB4 = f4add(runB4, f4sub(sB4, b4_##K));  b4_##K = sB4;            \
        runB1 += sB1 - b1_##K;                     b1_##K = sB1;            \
        if ((P) >= 2 * RAD) { EMIT(runA4, runA1); EMIT(runB4, runB1); }     \
    } while (0)

#define BODY(K) { YSTEP(idx - 1, K); XPHASE(idx); LOAD(idx + 1);            \
                  LDS_BARRIER(); ++idx; }

    // Pipeline: [y(idx-1) | x(idx) | load(idx+1) | lds-barrier] per slice.
    LOAD(0);
    XPHASE(0);
    LOAD(1);
    LDS_BARRIER();

    int idx = 1;
    #pragma unroll 1
    for (int g = 0; g < 4; ++g) {        // y-index p=idx-1 = 0..35, K=p%9
        BODY(0) BODY(1) BODY(2) BODY(3) BODY(4)
        BODY(5) BODY(6) BODY(7) BODY(8)
    }
    BODY(0) BODY(1) BODY(2)              // p = 36,37,38 -> K 0,1,2
    YSTEP(NSL - 1, 3);                   // p = 39 -> 39%9 = 3
#undef BODY
#undef YSTEP
#undef EMIT

    // Block reduction: wave shuffle -> LDS -> one double atomic.
    // (Full __syncthreads here is fine: once per block, nothing to prefetch.)
    float v = acc;
    #pragma unroll
    for (int off = 32; off >= 1; off >>= 1)
        v += __shfl_down(v, off, 64);
    const int lane = tid & 63;
    const int wid  = tid >> 6;
    if (lane == 0) red[wid] = v;
    __syncthreads();
    if (tid == 0) {
        atomicAdd(ws, (double)(red[0] + red[1] + red[2] + red[3]));
    }
}

extern "C" void kernel_launch(void* const* d_in, const int* in_sizes, int n_in,
                              void* d_out, int out_size, void* d_ws, size_t ws_size,
                              hipStream_t stream) {
    const float* I = (const float*)d_in[0];   // y_pred
    const float* J = (const float*)d_in[1];   // y_true
    double* ws = (double*)d_ws;
    float* out = (float*)d_out;

    hipLaunchKernelGGL(ncc_init, dim3(1), dim3(1), 0, stream, ws);

    hipLaunchKernelGGL(ncc_main, dim3(12 * 6 * 12), dim3(NTHR), 0, stream,
                       I, J, ws);

    hipLaunchKernelGGL(ncc_final, dim3(1), dim3(1), 0, stream, ws, out);
}